// Round 6
// baseline (2215.900 us; speedup 1.0000x reference)
//
#include <hip/hip_runtime.h>
#include <hip/hip_bf16.h>
#include <math.h>

typedef __hip_bfloat16 bf16;

// Problem constants (fixed by reference)
#define B_      8
#define S_      2048
#define DIN     1024
#define DSTATE  1024
#define H_      16
#define DH_     64
#define PROJ4   4096   // 4*DSTATE
#define NT1     4096   // GEMM1 tiles: 128 rowchunks x 32 coltiles
#define NU2     128    // GEMM2 units: one per (b,tc) rowchunk

// Barrier that does NOT drain vmcnt: LDS ordering only.
#define BARRIER_LGKM() asm volatile("s_waitcnt lgkmcnt(0)\n\ts_barrier" ::: "memory")

// ---------------------------------------------------------------------------
// Pipeline flags (device globals; zeroed by zero_flags each launch).
// ---------------------------------------------------------------------------
__device__ int g_q1;        // GEMM1 tile queue counter
__device__ int g_q2;        // GEMM2 unit queue counter
__device__ int g_rc[128];   // per-rowchunk GEMM1 tiles-done count (32 = ready)
__device__ int g_rd[128];   // per-rowchunk recur chains-done count (16 = ready)

__global__ void zero_flags() {
    int i = threadIdx.x;
    if (i == 0) { g_q1 = 0; g_q2 = 0; }
    if (i < 128) { g_rc[i] = 0; g_rd[i] = 0; }
}

// ---------------------------------------------------------------------------
// bf16 <-> f32 helpers (bit-level, RNE for store)
// ---------------------------------------------------------------------------
__device__ __forceinline__ unsigned short f2bf(float f) {
    unsigned int x = __float_as_uint(f);
    x += 0x7FFFu + ((x >> 16) & 1u);   // round-to-nearest-even
    return (unsigned short)(x >> 16);
}

__device__ __forceinline__ float4 load4(const float* p) { return *(const float4*)p; }
__device__ __forceinline__ float4 load4(const bf16* p) {
    uint2 u = *(const uint2*)p;    // 4 bf16 = 8 bytes
    float4 r;
    r.x = __uint_as_float((u.x & 0xFFFFu) << 16);
    r.y = __uint_as_float(u.x & 0xFFFF0000u);
    r.z = __uint_as_float((u.y & 0xFFFFu) << 16);
    r.w = __uint_as_float(u.y & 0xFFFF0000u);
    return r;
}
__device__ __forceinline__ void store4(float* p, float4 v) { *(float4*)p = v; }
__device__ __forceinline__ void store4(bf16* p, float4 v) {
    uint2 u;
    u.x = (unsigned int)f2bf(v.x) | ((unsigned int)f2bf(v.y) << 16);
    u.y = (unsigned int)f2bf(v.z) | ((unsigned int)f2bf(v.w) << 16);
    *(uint2*)p = u;
}

typedef __attribute__((ext_vector_type(8))) short bf16x8;
typedef __attribute__((ext_vector_type(4))) float f32x4;
typedef __attribute__((ext_vector_type(4))) short short4v;

template <typename TA>
__device__ __forceinline__ void load_a4(const TA* p, float out[4]);
template <>
__device__ __forceinline__ void load_a4<float>(const float* p, float out[4]) {
    float4 v = *(const float4*)p;
    out[0] = v.x; out[1] = v.y; out[2] = v.z; out[3] = v.w;
}
template <>
__device__ __forceinline__ void load_a4<bf16>(const bf16* p, float out[4]) {
    float4 v = load4(p);
    out[0] = v.x; out[1] = v.y; out[2] = v.z; out[3] = v.w;
}

// ---------------------------------------------------------------------------
// MFMA bf16 GEMM tile (device function): C[m0:m0+128, n0:n0+128] over full K.
// Same 128x128 tile / BK=32 / 4-wave scheme as before; As/Bs carved from smem.
// ---------------------------------------------------------------------------
template <typename TA, typename TC>
__device__ void gemm_tile(const TA* __restrict__ A, const float* __restrict__ Bm,
                          TC* __restrict__ C, int N, int K, int lda,
                          int m0, int n0, short* As, short* Bs) {
    const int tid = threadIdx.x;
    const int saM = tid >> 1;              // 0..127
    const int saK = (tid & 1) * 16;        // 0 or 16
    const int sbK = tid >> 3;              // 0..31
    const int sbN = (tid & 7) * 16;        // 0..112
    const int wid = tid >> 6;
    const int wx = wid & 1, wy = wid >> 1; // 2x2 wave grid
    const int lane = tid & 63;
    const int c16 = lane & 15;
    const int quad = lane >> 4;

    const TA* Aptr = A + (size_t)(m0 + saM) * lda + saK;
    const float* Bptr = Bm + (size_t)sbK * N + n0 + sbN;

    f32x4 acc[4][4];
    #pragma unroll
    for (int i = 0; i < 4; ++i)
        #pragma unroll
        for (int j = 0; j < 4; ++j) acc[i][j] = (f32x4){0.f, 0.f, 0.f, 0.f};

    float ra[4][4];
    float rb[4][4];
    #pragma unroll
    for (int i = 0; i < 4; ++i) load_a4<TA>(Aptr + i * 4, ra[i]);
    #pragma unroll
    for (int i = 0; i < 4; ++i) {
        float4 v = load4(Bptr + i * 4);
        rb[i][0] = v.x; rb[i][1] = v.y; rb[i][2] = v.z; rb[i][3] = v.w;
    }

    for (int k0 = 0; k0 < K; k0 += 32) {
        __syncthreads();
        #pragma unroll
        for (int i = 0; i < 4; ++i) {
            short4v pk = { (short)f2bf(ra[i][0]), (short)f2bf(ra[i][1]),
                           (short)f2bf(ra[i][2]), (short)f2bf(ra[i][3]) };
            *(short4v*)&As[saM * 40 + saK + i * 4] = pk;
        }
        #pragma unroll
        for (int i = 0; i < 4; ++i)
            #pragma unroll
            for (int j = 0; j < 4; ++j)
                Bs[(sbN + i * 4 + j) * 40 + sbK] = (short)f2bf(rb[i][j]);
        __syncthreads();

        if (k0 + 32 < K) {
            #pragma unroll
            for (int i = 0; i < 4; ++i) load_a4<TA>(Aptr + k0 + 32 + i * 4, ra[i]);
            #pragma unroll
            for (int i = 0; i < 4; ++i) {
                float4 v = load4(Bptr + (size_t)(k0 + 32) * N + i * 4);
                rb[i][0] = v.x; rb[i][1] = v.y; rb[i][2] = v.z; rb[i][3] = v.w;
            }
        }

        bf16x8 af[4], bfr[4];
        #pragma unroll
        for (int mt = 0; mt < 4; ++mt)
            af[mt] = *(const bf16x8*)&As[(wy * 64 + mt * 16 + c16) * 40 + quad * 8];
        #pragma unroll
        for (int nt = 0; nt < 4; ++nt)
            bfr[nt] = *(const bf16x8*)&Bs[(wx * 64 + nt * 16 + c16) * 40 + quad * 8];

        #pragma unroll
        for (int mt = 0; mt < 4; ++mt)
            #pragma unroll
            for (int nt = 0; nt < 4; ++nt)
                acc[mt][nt] = __builtin_amdgcn_mfma_f32_16x16x32_bf16(
                    af[mt], bfr[nt], acc[mt][nt], 0, 0, 0);
    }

    #pragma unroll
    for (int mt = 0; mt < 4; ++mt) {
        #pragma unroll
        for (int r = 0; r < 4; ++r) {
            int row = m0 + wy * 64 + mt * 16 + quad * 4 + r;
            TC* cp = C + (size_t)row * N + n0 + wx * 64;
            #pragma unroll
            for (int nt = 0; nt < 4; ++nt)
                cp[nt * 16 + c16] = (TC)acc[mt][nt][r];
        }
    }
}

// ---------------------------------------------------------------------------
// Gated RMSNorm for one row (256 threads), in place over proj cols [0:1024).
// ---------------------------------------------------------------------------
__device__ __forceinline__ void gn_row(bf16* __restrict__ proj,
                                       const float* __restrict__ nw,
                                       int row, float* red) {
    const int tid = threadIdx.x;
    bf16* hp = proj + (size_t)row * PROJ4;
    const bf16* gp = hp + 3 * DSTATE;

    float4 hv = load4(hp + tid * 4);
    float4 gv = load4(gp + tid * 4);

    float v0 = hv.x * (gv.x / (1.f + __expf(-gv.x)));
    float v1 = hv.y * (gv.y / (1.f + __expf(-gv.y)));
    float v2 = hv.z * (gv.z / (1.f + __expf(-gv.z)));
    float v3 = hv.w * (gv.w / (1.f + __expf(-gv.w)));

    float ss = v0 * v0 + v1 * v1 + v2 * v2 + v3 * v3;
    #pragma unroll
    for (int mask = 32; mask >= 1; mask >>= 1)
        ss += __shfl_xor(ss, mask, 64);

    if ((tid & 63) == 0) red[tid >> 6] = ss;
    __syncthreads();
    float tot = red[0] + red[1] + red[2] + red[3];
    float scale = rsqrtf(tot * (1.0f / (float)DSTATE) + 1e-6f);

    float4 nv = *(const float4*)(nw + tid * 4);
    float4 y;
    y.x = v0 * scale * nv.x;
    y.y = v1 * scale * nv.y;
    y.z = v2 * scale * nv.z;
    y.w = v3 * scale * nv.w;
    store4(hp + tid * 4, y);
    __syncthreads();   // red reuse next row
}

// ---------------------------------------------------------------------------
// Fused pipeline kernel. Grid = 256 blocks x 256 threads (1 block/CU):
//  blocks 0..127  : recur chains (b,h), 4 waves, v5 step structure, chunked
//                   by 128 steps; spin on g_rc[rowchunk] (GEMM1 done) before
//                   each chunk; publish g_rd[rowchunk] after.
//  blocks 128..255: workers. Stage 1: drain GEMM1 tile queue (t-chunk-major
//                   order) -> flag g_rc. Stage 2: claim (b,tc) units, spin on
//                   g_rd==16, gate-norm 128 rows + 8 GEMM2 tiles -> out.
// Deadlock-free: stage-1 workers never wait; recur waits only on stage 1;
// stage 2 waits only on recur. Cross-XCD visibility: __threadfence (L2 wb)
// before flag-add; agent-scope atomic spin + __threadfence (inv) after.
// LDS sized 56KB -> 2 blocks/CU cap -> RA register budget 256 (both paths).
// ---------------------------------------------------------------------------
__device__ __forceinline__ float lane_bcast(float v, int lane) {
    return __int_as_float(__builtin_amdgcn_readlane(__float_as_int(v), lane));
}

#define RPT16(M) M(0) M(1) M(2) M(3) M(4) M(5) M(6) M(7) \
                 M(8) M(9) M(10) M(11) M(12) M(13) M(14) M(15)

__global__ __launch_bounds__(256) void fused_kernel(
        const float* __restrict__ x, const float* __restrict__ w_in,
        const float* __restrict__ sw, const float* __restrict__ nw,
        const float* __restrict__ w_out, bf16* __restrict__ proj,
        float* __restrict__ out) {
    __shared__ __align__(16) char smem[57344];
    const int tid = threadIdx.x;
    const int bid = blockIdx.x;

    if (bid < 128) {
        // ------------------------- recur role -------------------------
        float2* prf = (float2*)smem;           // [4][64] (r,f) partials
        float*  pc  = (float*)(smem + 2048);   // [4][64] c partials

        const int e = tid & 63;
        const int w = __builtin_amdgcn_readfirstlane(tid >> 6);   // 0..3
        const int d0 = w << 4;
        const int b = bid >> 4;
        const int h = bid & 15;

        const float* Wc_p = sw + (size_t)h * 4096 + (size_t)d0 * 64 + e;
        const float* Wf_p = Wc_p + (size_t)16 * 4096;
        const float* Wr_p = Wc_p + (size_t)32 * 4096;

        #define DECLW(i) float wc##i, wf##i, wr##i;
        RPT16(DECLW)
        #undef DECLW
        #define LOADW(i) wc##i = Wc_p[(i) * 64]; \
                         wf##i = Wf_p[(i) * 64]; \
                         wr##i = Wr_p[(i) * 64];
        RPT16(LOADW)
        #undef LOADW
        #define PINW(i) asm volatile("" : "+v"(wc##i), "+v"(wf##i), "+v"(wr##i));
        RPT16(PINW)
        #undef PINW

        bf16* xi_p = proj + (size_t)b * S_ * PROJ4 + h * 64 + e;
        float hreg = 0.0f;

        #define P1T(i, A) { float hb = lane_bcast(hreg, d0 + (i)); \
            aR##A = fmaf(hb, wr##i, aR##A); \
            aF##A = fmaf(hb, wf##i, aF##A); }
        #define P2T(i, A) { float qb = lane_bcast(rh, d0 + (i)); \
            aC##A = fmaf(qb, wc##i, aC##A); }

        #define STEP(U, REFILL) { \
            float xi0 = rxi[U], xf0 = rxf[U], xr0 = rxr[U]; \
            if (REFILL) { \
                const bf16* p = ld + (size_t)(U) * PROJ4; \
                rxi[U] = __bfloat162float(p[0]); \
                rxf[U] = __bfloat162float(p[1024]); \
                rxr[U] = __bfloat162float(p[2048]); \
            } \
            float aR0 = 0.f, aR1 = 0.f, aF0 = 0.f, aF1 = 0.f; \
            P1T(0,0)  P1T(1,1)  P1T(2,0)  P1T(3,1) \
            P1T(4,0)  P1T(5,1)  P1T(6,0)  P1T(7,1) \
            P1T(8,0)  P1T(9,1)  P1T(10,0) P1T(11,1) \
            P1T(12,0) P1T(13,1) P1T(14,0) P1T(15,1) \
            prf[w * 64 + e] = make_float2(aR0 + aR1, aF0 + aF1); \
            BARRIER_LGKM(); \
            float2 p0 = prf[0 * 64 + e], p1 = prf[1 * 64 + e]; \
            float2 p2 = prf[2 * 64 + e], p3 = prf[3 * 64 + e]; \
            float sr = xr0 + (p0.x + p1.x) + (p2.x + p3.x); \
            float sf = xf0 + (p0.y + p1.y) + (p2.y + p3.y); \
            float r = 1.f / (1.f + __expf(-sr)); \
            float f = 1.f / (1.f + __expf(-sf)); \
            float rh = r * hreg; \
            float aC0 = 0.f, aC1 = 0.f; \
            P2T(0,0)  P2T(1,1)  P2T(2,0)  P2T(3,1) \
            P2T(4,0)  P2T(5,1)  P2T(6,0)  P2T(7,1) \
            P2T(8,0)  P2T(9,1)  P2T(10,0) P2T(11,1) \
            P2T(12,0) P2T(13,1) P2T(14,0) P2T(15,1) \
            pc[w * 64 + e] = aC0 + aC1; \
            BARRIER_LGKM(); \
            float sc = xi0 + (pc[0 * 64 + e] + pc[1 * 64 + e]) \
                           + (pc[2 * 64 + e] + pc[3 * 64 + e]); \
            sc = fminf(fmaxf(sc, -15.f), 15.f); \
            float ex = __expf(-2.f * sc); \
            float cc = (1.f - ex) / (1.f + ex); \
            hreg = f * hreg + (1.f - f) * cc; \
            if (w == (U)) st[(size_t)(U) * PROJ4] = __float2bfloat16(hreg); \
        }

        for (int tc = 0; tc < 16; ++tc) {
            const int mIdx = b * 16 + tc;
            if (tid == 0) {
                while (__hip_atomic_load(&g_rc[mIdx], __ATOMIC_RELAXED,
                                         __HIP_MEMORY_SCOPE_AGENT) < 32)
                    __builtin_amdgcn_s_sleep(8);
            }
            __syncthreads();
            __threadfence();   // acquire: invalidate stale cache lines

            bf16* xrow = xi_p + (size_t)(tc * 128) * PROJ4;
            f32x4 rxi, rxf, rxr;
            #define PRELOAD(U) { const bf16* p = xrow + (size_t)(U) * PROJ4; \
                rxi[U] = __bfloat162float(p[0]); \
                rxf[U] = __bfloat162float(p[1024]); \
                rxr[U] = __bfloat162float(p[2048]); }
            PRELOAD(0) PRELOAD(1) PRELOAD(2) PRELOAD(3)
            #undef PRELOAD

            const bf16* ld = xrow + (size_t)4 * PROJ4;
            bf16*       st = xrow;

            for (int t0 = 0; t0 < 124; t0 += 4) {
                STEP(0, 1) STEP(1, 1) STEP(2, 1) STEP(3, 1)
                ld += (size_t)4 * PROJ4;
                st += (size_t)4 * PROJ4;
            }
            STEP(0, 0) STEP(1, 0) STEP(2, 0) STEP(3, 0)

            __syncthreads();   // drains vmcnt: all h-stores of chunk complete
            if (tid == 0) {
                __threadfence();                // release: L2 writeback
                atomicAdd(&g_rd[mIdx], 1);
            }
        }
        #undef STEP
        #undef P1T
        #undef P2T
    } else {
        // ------------------------- worker role -------------------------
        short* As   = (short*)smem;                  // [128][40]
        short* Bs   = (short*)(smem + 10240);        // [128][40]
        int*  taskp = (int*)(smem + 20480);
        float* red  = (float*)(smem + 20484);

        // Stage 1: GEMM1 tile queue, t-chunk-major order. Never waits.
        for (;;) {
            __syncthreads();
            if (tid == 0) *taskp = atomicAdd(&g_q1, 1);
            __syncthreads();
            int id = *taskp;
            if (id >= NT1) break;
            int tc = id >> 8;
            int rem = id & 255;
            int bb = rem >> 5;
            int n = rem & 31;
            int mIdx = bb * 16 + tc;
            gemm_tile<float, bf16>(x, w_in, proj, PROJ4, DIN, DIN,
                                   mIdx * 128, n * 128, As, Bs);
            __syncthreads();   // drains vmcnt: tile stores complete
            if (tid == 0) {
                __threadfence();                // release
                atomicAdd(&g_rc[mIdx], 1);
            }
        }

        // Stage 2: per-(b,tc) units: gate-norm 128 rows + 8 GEMM2 tiles.
        for (;;) {
            __syncthreads();
            if (tid == 0) *taskp = atomicAdd(&g_q2, 1);
            __syncthreads();
            int id = *taskp;
            if (id >= NU2) break;
            int tc = id >> 3;
            int bb = id & 7;
            int mIdx = bb * 16 + tc;
            if (tid == 0) {
                while (__hip_atomic_load(&g_rd[mIdx], __ATOMIC_RELAXED,
                                         __HIP_MEMORY_SCOPE_AGENT) < 16)
                    __builtin_amdgcn_s_sleep(8);
            }
            __syncthreads();
            __threadfence();   // acquire

            int rbase = mIdx * 128;
            for (int r = 0; r < 128; ++r) gn_row(proj, nw, rbase + r, red);
            __syncthreads();   // drains vmcnt: gn stores complete before reads

            for (int nt = 0; nt < 8; ++nt)
                gemm_tile<bf16, float>(proj, w_out, out, DSTATE, DSTATE, PROJ4,
                                       rbase, nt * 128, As, Bs);
        }
    }
}

// ---------------------------------------------------------------------------
extern "C" void kernel_launch(void* const* d_in, const int* in_sizes, int n_in,
                              void* d_out, int out_size, void* d_ws, size_t ws_size,
                              hipStream_t stream) {
    const float* x     = (const float*)d_in[0];   // [B,S,DIN]
    const float* w_in  = (const float*)d_in[1];   // [DIN, 4*DSTATE]
    const float* sw    = (const float*)d_in[2];   // [3H, DH, DH]
    const float* nw    = (const float*)d_in[3];   // [DSTATE]
    const float* w_out = (const float*)d_in[4];   // [DSTATE, DOUT]
    float* out = (float*)d_out;

    bf16* proj = (bf16*)d_ws;    // [B*S, 4096] bf16 = 134 MB

    zero_flags<<<1, 128, 0, stream>>>();
    fused_kernel<<<256, 256, 0, stream>>>(x, w_in, sw, nw, w_out, proj, out);
}

// Round 7
// 1943.969 us; speedup vs baseline: 1.1399x; 1.1399x over previous
//
#include <hip/hip_runtime.h>
#include <hip/hip_bf16.h>
#include <math.h>

typedef __hip_bfloat16 bf16;

// Problem constants (fixed by reference)
#define B_      8
#define S_      2048
#define DIN     1024
#define DSTATE  1024
#define H_      16
#define DH_     64
#define PROJ4   4096   // 4*DSTATE
#define NT1     4096   // GEMM1 tiles: 16 tchunks x 8 b x 32 n
#define NU_GN   128    // gn units: (tc, b)
#define NT2     1024   // GEMM2 tiles: (tc, b, nt)

// Barrier that does NOT drain vmcnt: LDS ordering only.
#define BARRIER_LGKM() asm volatile("s_waitcnt lgkmcnt(0)\n\ts_barrier" ::: "memory")

// ---------------------------------------------------------------------------
// Pipeline flags (device globals; zeroed by zero_flags each launch).
// ---------------------------------------------------------------------------
__device__ int g_q1;        // GEMM1 tile queue
__device__ int g_q2;        // gn unit queue
__device__ int g_q3;        // GEMM2 tile queue
__device__ int g_rc[128];   // per-(b,tc) GEMM1 tiles done (32 = x ready)
__device__ int g_rd[128];   // per-(b,tc) recur chains done (16 = h ready)
__device__ int g_gn[128];   // per-(b,tc) gate-norm done (1 = ready)

__global__ void zero_flags() {
    int i = threadIdx.x;
    if (i == 0) { g_q1 = 0; g_q2 = 0; g_q3 = 0; }
    if (i < 128) { g_rc[i] = 0; g_rd[i] = 0; g_gn[i] = 0; }
}

// ---------------------------------------------------------------------------
// bf16 <-> f32 helpers (bit-level, RNE for store)
// ---------------------------------------------------------------------------
__device__ __forceinline__ unsigned short f2bf(float f) {
    unsigned int x = __float_as_uint(f);
    x += 0x7FFFu + ((x >> 16) & 1u);   // round-to-nearest-even
    return (unsigned short)(x >> 16);
}

__device__ __forceinline__ float4 load4(const float* p) { return *(const float4*)p; }
__device__ __forceinline__ float4 load4(const bf16* p) {
    uint2 u = *(const uint2*)p;    // 4 bf16 = 8 bytes
    float4 r;
    r.x = __uint_as_float((u.x & 0xFFFFu) << 16);
    r.y = __uint_as_float(u.x & 0xFFFF0000u);
    r.z = __uint_as_float((u.y & 0xFFFFu) << 16);
    r.w = __uint_as_float(u.y & 0xFFFF0000u);
    return r;
}
__device__ __forceinline__ void store4(float* p, float4 v) { *(float4*)p = v; }
__device__ __forceinline__ void store4(bf16* p, float4 v) {
    uint2 u;
    u.x = (unsigned int)f2bf(v.x) | ((unsigned int)f2bf(v.y) << 16);
    u.y = (unsigned int)f2bf(v.z) | ((unsigned int)f2bf(v.w) << 16);
    *(uint2*)p = u;
}

typedef __attribute__((ext_vector_type(8))) short bf16x8;
typedef __attribute__((ext_vector_type(4))) float f32x4;
typedef __attribute__((ext_vector_type(4))) short short4v;

template <typename TA>
__device__ __forceinline__ void load_a4(const TA* p, float out[4]);
template <>
__device__ __forceinline__ void load_a4<float>(const float* p, float out[4]) {
    float4 v = *(const float4*)p;
    out[0] = v.x; out[1] = v.y; out[2] = v.z; out[3] = v.w;
}
template <>
__device__ __forceinline__ void load_a4<bf16>(const bf16* p, float out[4]) {
    float4 v = load4(p);
    out[0] = v.x; out[1] = v.y; out[2] = v.z; out[3] = v.w;
}

// ---------------------------------------------------------------------------
// MFMA bf16 GEMM tile (device fn): C[m0:+128, n0:+128] over full K.
// ---------------------------------------------------------------------------
template <typename TA, typename TC>
__device__ void gemm_tile(const TA* __restrict__ A, const float* __restrict__ Bm,
                          TC* __restrict__ C, int N, int K, int lda,
                          int m0, int n0, short* As, short* Bs) {
    const int tid = threadIdx.x;
    const int saM = tid >> 1;
    const int saK = (tid & 1) * 16;
    const int sbK = tid >> 3;
    const int sbN = (tid & 7) * 16;
    const int wid = tid >> 6;
    const int wx = wid & 1, wy = wid >> 1;
    const int lane = tid & 63;
    const int c16 = lane & 15;
    const int quad = lane >> 4;

    const TA* Aptr = A + (size_t)(m0 + saM) * lda + saK;
    const float* Bptr = Bm + (size_t)sbK * N + n0 + sbN;

    f32x4 acc[4][4];
    #pragma unroll
    for (int i = 0; i < 4; ++i)
        #pragma unroll
        for (int j = 0; j < 4; ++j) acc[i][j] = (f32x4){0.f, 0.f, 0.f, 0.f};

    float ra[4][4];
    float rb[4][4];
    #pragma unroll
    for (int i = 0; i < 4; ++i) load_a4<TA>(Aptr + i * 4, ra[i]);
    #pragma unroll
    for (int i = 0; i < 4; ++i) {
        float4 v = load4(Bptr + i * 4);
        rb[i][0] = v.x; rb[i][1] = v.y; rb[i][2] = v.z; rb[i][3] = v.w;
    }

    for (int k0 = 0; k0 < K; k0 += 32) {
        __syncthreads();
        #pragma unroll
        for (int i = 0; i < 4; ++i) {
            short4v pk = { (short)f2bf(ra[i][0]), (short)f2bf(ra[i][1]),
                           (short)f2bf(ra[i][2]), (short)f2bf(ra[i][3]) };
            *(short4v*)&As[saM * 40 + saK + i * 4] = pk;
        }
        #pragma unroll
        for (int i = 0; i < 4; ++i)
            #pragma unroll
            for (int j = 0; j < 4; ++j)
                Bs[(sbN + i * 4 + j) * 40 + sbK] = (short)f2bf(rb[i][j]);
        __syncthreads();

        if (k0 + 32 < K) {
            #pragma unroll
            for (int i = 0; i < 4; ++i) load_a4<TA>(Aptr + k0 + 32 + i * 4, ra[i]);
            #pragma unroll
            for (int i = 0; i < 4; ++i) {
                float4 v = load4(Bptr + (size_t)(k0 + 32) * N + i * 4);
                rb[i][0] = v.x; rb[i][1] = v.y; rb[i][2] = v.z; rb[i][3] = v.w;
            }
        }

        bf16x8 af[4], bfr[4];
        #pragma unroll
        for (int mt = 0; mt < 4; ++mt)
            af[mt] = *(const bf16x8*)&As[(wy * 64 + mt * 16 + c16) * 40 + quad * 8];
        #pragma unroll
        for (int nt = 0; nt < 4; ++nt)
            bfr[nt] = *(const bf16x8*)&Bs[(wx * 64 + nt * 16 + c16) * 40 + quad * 8];

        #pragma unroll
        for (int mt = 0; mt < 4; ++mt)
            #pragma unroll
            for (int nt = 0; nt < 4; ++nt)
                acc[mt][nt] = __builtin_amdgcn_mfma_f32_16x16x32_bf16(
                    af[mt], bfr[nt], acc[mt][nt], 0, 0, 0);
    }

    #pragma unroll
    for (int mt = 0; mt < 4; ++mt) {
        #pragma unroll
        for (int r = 0; r < 4; ++r) {
            int row = m0 + wy * 64 + mt * 16 + quad * 4 + r;
            TC* cp = C + (size_t)row * N + n0 + wx * 64;
            #pragma unroll
            for (int nt = 0; nt < 4; ++nt)
                cp[nt * 16 + c16] = (TC)acc[mt][nt][r];
        }
    }
}

// ---------------------------------------------------------------------------
// Gated RMSNorm, wave-parallel: each wave owns rows r%4==w of the 128-row
// chunk; per-row reduce is a 64-lane shfl (no barriers, 4 rows in flight).
// ---------------------------------------------------------------------------
__device__ void gn_unit(bf16* __restrict__ proj, const float* __restrict__ nw,
                        int rbase) {
    const int lane = threadIdx.x & 63;
    const int w = threadIdx.x >> 6;
    for (int r = w; r < 128; r += 4) {
        bf16* hp = proj + (size_t)(rbase + r) * PROJ4;
        const bf16* gp = hp + 3 * DSTATE;
        float v[16];
        float ss = 0.f;
        #pragma unroll
        for (int k = 0; k < 4; ++k) {
            float4 hh = load4(hp + lane * 4 + k * 256);
            float4 gg = load4(gp + lane * 4 + k * 256);
            float t0 = hh.x * (gg.x / (1.f + __expf(-gg.x)));
            float t1 = hh.y * (gg.y / (1.f + __expf(-gg.y)));
            float t2 = hh.z * (gg.z / (1.f + __expf(-gg.z)));
            float t3 = hh.w * (gg.w / (1.f + __expf(-gg.w)));
            v[k * 4 + 0] = t0; v[k * 4 + 1] = t1;
            v[k * 4 + 2] = t2; v[k * 4 + 3] = t3;
            ss += t0 * t0 + t1 * t1 + t2 * t2 + t3 * t3;
        }
        #pragma unroll
        for (int m = 32; m >= 1; m >>= 1) ss += __shfl_xor(ss, m, 64);
        float scale = rsqrtf(ss * (1.0f / (float)DSTATE) + 1e-6f);
        #pragma unroll
        for (int k = 0; k < 4; ++k) {
            float4 nv = *(const float4*)(nw + lane * 4 + k * 256);
            float4 y;
            y.x = v[k * 4 + 0] * scale * nv.x;
            y.y = v[k * 4 + 1] * scale * nv.y;
            y.z = v[k * 4 + 2] * scale * nv.z;
            y.w = v[k * 4 + 3] * scale * nv.w;
            store4(hp + lane * 4 + k * 256, y);
        }
    }
}

// ---------------------------------------------------------------------------
// GEMM2 tile-queue drain (workers after q2; recur blocks after their chains).
// ---------------------------------------------------------------------------
__device__ void drain_q3(const bf16* __restrict__ proj,
                         const float* __restrict__ w_out,
                         float* __restrict__ out,
                         short* As, short* Bs, int* taskp) {
    for (;;) {
        __syncthreads();
        if (threadIdx.x == 0) *taskp = atomicAdd(&g_q3, 1);
        __syncthreads();
        int id = *taskp;
        if (id >= NT2) break;
        int tc = id >> 6, rem = id & 63, bb = rem >> 3, nt = rem & 7;
        int mIdx = bb * 16 + tc;
        if (threadIdx.x == 0) {
            while (__hip_atomic_load(&g_gn[mIdx], __ATOMIC_RELAXED,
                                     __HIP_MEMORY_SCOPE_AGENT) < 1)
                __builtin_amdgcn_s_sleep(8);
        }
        __syncthreads();
        __threadfence();   // acquire
        gemm_tile<bf16, float>(proj, w_out, out, DSTATE, DSTATE, PROJ4,
                               mIdx * 128, nt * 128, As, Bs);
    }
}

// ---------------------------------------------------------------------------
// Fused pipeline. Grid = 384 blocks x 256 threads:
//  blocks 0..127  : recur chains (b,h); per 128-step chunk: wait g_rc==32,
//                   run, flag g_rd; after all chunks, join q3 (GEMM2 tiles).
//  blocks 128..383: workers (2/CU -> restores inter-block GEMM overlap that
//                   R6's 1-block/CU lost). Drain q1 (GEMM1 tiles, tc-major)
//                   -> q2 (gn units, wait g_rd==16) -> q3 (GEMM2 tiles,
//                   wait g_gn).
// Deadlock-free (acyclic waits: q1 never waits; recur<-q1; q2<-recur;
// q3<-q2); all 384 blocks trivially co-resident (20.5 KB LDS, 4 waves).
// Cross-XCD: __threadfence release before flag-add; agent-scope atomic spin
// + __threadfence acquire after (same discipline that passed in R6).
// ---------------------------------------------------------------------------
__device__ __forceinline__ float lane_bcast(float v, int lane) {
    return __int_as_float(__builtin_amdgcn_readlane(__float_as_int(v), lane));
}

#define RPT16(M) M(0) M(1) M(2) M(3) M(4) M(5) M(6) M(7) \
                 M(8) M(9) M(10) M(11) M(12) M(13) M(14) M(15)

__global__ __launch_bounds__(256) void fused_kernel(
        const float* __restrict__ x, const float* __restrict__ w_in,
        const float* __restrict__ sw, const float* __restrict__ nw,
        const float* __restrict__ w_out, bf16* __restrict__ proj,
        float* __restrict__ out) {
    __shared__ __align__(16) char smem[20544];
    const int tid = threadIdx.x;
    const int bid = blockIdx.x;

    short* As   = (short*)smem;              // [128][40] (worker/q3 phases)
    short* Bs   = (short*)(smem + 10240);    // [128][40]
    int*  taskp = (int*)(smem + 20480);

    if (bid < 128) {
        // ------------------------- recur role -------------------------
        float2* prf = (float2*)smem;           // [4][64] (r,f) partials
        float*  pc  = (float*)(smem + 2048);   // [4][64] c partials

        const int e = tid & 63;
        const int w = __builtin_amdgcn_readfirstlane(tid >> 6);   // 0..3
        const int d0 = w << 4;
        const int b = bid >> 4;
        const int h = bid & 15;

        const float* Wc_p = sw + (size_t)h * 4096 + (size_t)d0 * 64 + e;
        const float* Wf_p = Wc_p + (size_t)16 * 4096;
        const float* Wr_p = Wc_p + (size_t)32 * 4096;

        #define DECLW(i) float wc##i, wf##i, wr##i;
        RPT16(DECLW)
        #undef DECLW
        #define LOADW(i) wc##i = Wc_p[(i) * 64]; \
                         wf##i = Wf_p[(i) * 64]; \
                         wr##i = Wr_p[(i) * 64];
        RPT16(LOADW)
        #undef LOADW
        #define PINW(i) asm volatile("" : "+v"(wc##i), "+v"(wf##i), "+v"(wr##i));
        RPT16(PINW)
        #undef PINW

        bf16* xi_p = proj + (size_t)b * S_ * PROJ4 + h * 64 + e;
        float hreg = 0.0f;

        #define P1T(i, A) { float hb = lane_bcast(hreg, d0 + (i)); \
            aR##A = fmaf(hb, wr##i, aR##A); \
            aF##A = fmaf(hb, wf##i, aF##A); }
        #define P2T(i, A) { float qb = lane_bcast(rh, d0 + (i)); \
            aC##A = fmaf(qb, wc##i, aC##A); }

        #define STEP(U, REFILL) { \
            float xi0 = rxi[U], xf0 = rxf[U], xr0 = rxr[U]; \
            if (REFILL) { \
                const bf16* p = ld + (size_t)(U) * PROJ4; \
                rxi[U] = __bfloat162float(p[0]); \
                rxf[U] = __bfloat162float(p[1024]); \
                rxr[U] = __bfloat162float(p[2048]); \
            } \
            float aR0 = 0.f, aR1 = 0.f, aF0 = 0.f, aF1 = 0.f; \
            P1T(0,0)  P1T(1,1)  P1T(2,0)  P1T(3,1) \
            P1T(4,0)  P1T(5,1)  P1T(6,0)  P1T(7,1) \
            P1T(8,0)  P1T(9,1)  P1T(10,0) P1T(11,1) \
            P1T(12,0) P1T(13,1) P1T(14,0) P1T(15,1) \
            prf[w * 64 + e] = make_float2(aR0 + aR1, aF0 + aF1); \
            BARRIER_LGKM(); \
            float2 p0 = prf[0 * 64 + e], p1 = prf[1 * 64 + e]; \
            float2 p2 = prf[2 * 64 + e], p3 = prf[3 * 64 + e]; \
            float sr = xr0 + (p0.x + p1.x) + (p2.x + p3.x); \
            float sf = xf0 + (p0.y + p1.y) + (p2.y + p3.y); \
            float r = 1.f / (1.f + __expf(-sr)); \
            float f = 1.f / (1.f + __expf(-sf)); \
            float rh = r * hreg; \
            float aC0 = 0.f, aC1 = 0.f; \
            P2T(0,0)  P2T(1,1)  P2T(2,0)  P2T(3,1) \
            P2T(4,0)  P2T(5,1)  P2T(6,0)  P2T(7,1) \
            P2T(8,0)  P2T(9,1)  P2T(10,0) P2T(11,1) \
            P2T(12,0) P2T(13,1) P2T(14,0) P2T(15,1) \
            pc[w * 64 + e] = aC0 + aC1; \
            BARRIER_LGKM(); \
            float sc = xi0 + (pc[0 * 64 + e] + pc[1 * 64 + e]) \
                           + (pc[2 * 64 + e] + pc[3 * 64 + e]); \
            sc = fminf(fmaxf(sc, -15.f), 15.f); \
            float ex = __expf(-2.f * sc); \
            float cc = (1.f - ex) / (1.f + ex); \
            hreg = f * hreg + (1.f - f) * cc; \
            if (w == (U)) st[(size_t)(U) * PROJ4] = __float2bfloat16(hreg); \
        }

        for (int tc = 0; tc < 16; ++tc) {
            const int mIdx = b * 16 + tc;
            if (tid == 0) {
                while (__hip_atomic_load(&g_rc[mIdx], __ATOMIC_RELAXED,
                                         __HIP_MEMORY_SCOPE_AGENT) < 32)
                    __builtin_amdgcn_s_sleep(8);
            }
            __syncthreads();
            __threadfence();   // acquire

            bf16* xrow = xi_p + (size_t)(tc * 128) * PROJ4;
            f32x4 rxi, rxf, rxr;
            #define PRELOAD(U) { const bf16* p = xrow + (size_t)(U) * PROJ4; \
                rxi[U] = __bfloat162float(p[0]); \
                rxf[U] = __bfloat162float(p[1024]); \
                rxr[U] = __bfloat162float(p[2048]); }
            PRELOAD(0) PRELOAD(1) PRELOAD(2) PRELOAD(3)
            #undef PRELOAD

            const bf16* ld = xrow + (size_t)4 * PROJ4;
            bf16*       st = xrow;

            for (int t0 = 0; t0 < 124; t0 += 4) {
                STEP(0, 1) STEP(1, 1) STEP(2, 1) STEP(3, 1)
                ld += (size_t)4 * PROJ4;
                st += (size_t)4 * PROJ4;
            }
            STEP(0, 0) STEP(1, 0) STEP(2, 0) STEP(3, 0)

            __syncthreads();   // implies vmcnt drain: chunk h-stores done
            if (tid == 0) {
                __threadfence();                // release
                atomicAdd(&g_rd[mIdx], 1);
            }
        }
        #undef STEP
        #undef P1T
        #undef P2T

        // Chains done: help drain the GEMM2 tile queue (smem reused).
        __syncthreads();
        drain_q3(proj, w_out, out, As, Bs, taskp);
    } else {
        // ------------------------- worker role -------------------------
        // q1: GEMM1 tiles, tc-major. Never waits.
        for (;;) {
            __syncthreads();
            if (tid == 0) *taskp = atomicAdd(&g_q1, 1);
            __syncthreads();
            int id = *taskp;
            if (id >= NT1) break;
            int tc = id >> 8, rem = id & 255, bb = rem >> 5, n = rem & 31;
            int mIdx = bb * 16 + tc;
            gemm_tile<float, bf16>(x, w_in, proj, PROJ4, DIN, DIN,
                                   mIdx * 128, n * 128, As, Bs);
            __syncthreads();   // implies vmcnt drain
            if (tid == 0) {
                __threadfence();                // release
                atomicAdd(&g_rc[mIdx], 1);
            }
        }

        // q2: gate-norm units (tc-major), wait on recur.
        for (;;) {
            __syncthreads();
            if (tid == 0) *taskp = atomicAdd(&g_q2, 1);
            __syncthreads();
            int id = *taskp;
            if (id >= NU_GN) break;
            int tc = id >> 3, bb = id & 7;
            int mIdx = bb * 16 + tc;
            if (tid == 0) {
                while (__hip_atomic_load(&g_rd[mIdx], __ATOMIC_RELAXED,
                                         __HIP_MEMORY_SCOPE_AGENT) < 16)
                    __builtin_amdgcn_s_sleep(8);
            }
            __syncthreads();
            __threadfence();   // acquire
            gn_unit(proj, nw, mIdx * 128);
            __syncthreads();   // implies vmcnt drain
            if (tid == 0) {
                __threadfence();                // release
                atomicAdd(&g_gn[mIdx], 1);
            }
        }

        // q3: GEMM2 tiles, wait on gn.
        drain_q3(proj, w_out, out, As, Bs, taskp);
    }
}

// ---------------------------------------------------------------------------
extern "C" void kernel_launch(void* const* d_in, const int* in_sizes, int n_in,
                              void* d_out, int out_size, void* d_ws, size_t ws_size,
                              hipStream_t stream) {
    const float* x     = (const float*)d_in[0];   // [B,S,DIN]
    const float* w_in  = (const float*)d_in[1];   // [DIN, 4*DSTATE]
    const float* sw    = (const float*)d_in[2];   // [3H, DH, DH]
    const float* nw    = (const float*)d_in[3];   // [DSTATE]
    const float* w_out = (const float*)d_in[4];   // [DSTATE, DOUT]
    float* out = (float*)d_out;

    bf16* proj = (bf16*)d_ws;    // [B*S, 4096] bf16 = 134 MB

    zero_flags<<<1, 128, 0, stream>>>();
    fused_kernel<<<384, 256, 0, stream>>>(x, w_in, sw, nw, w_out, proj, out);
}

// Round 8
// 1481.947 us; speedup vs baseline: 1.4953x; 1.3118x over previous
//
#include <hip/hip_runtime.h>
#include <hip/hip_bf16.h>
#include <math.h>

typedef __hip_bfloat16 bf16;

// Problem constants (fixed by reference)
#define B_      8
#define S_      2048
#define DIN     1024
#define DSTATE  1024
#define H_      16
#define DH_     64
#define PROJ4   4096   // 4*DSTATE

// Barrier that does NOT drain vmcnt: LDS ordering only.
#define BARRIER_LGKM() asm volatile("s_waitcnt lgkmcnt(0)\n\ts_barrier" ::: "memory")

// ---------------------------------------------------------------------------
// bf16 <-> f32 helpers (bit-level, RNE for store)
// ---------------------------------------------------------------------------
__device__ __forceinline__ unsigned short f2bf(float f) {
    unsigned int x = __float_as_uint(f);
    x += 0x7FFFu + ((x >> 16) & 1u);   // round-to-nearest-even
    return (unsigned short)(x >> 16);
}

__device__ __forceinline__ float4 load4(const float* p) { return *(const float4*)p; }
__device__ __forceinline__ float4 load4(const bf16* p) {
    uint2 u = *(const uint2*)p;    // 4 bf16 = 8 bytes
    float4 r;
    r.x = __uint_as_float((u.x & 0xFFFFu) << 16);
    r.y = __uint_as_float(u.x & 0xFFFF0000u);
    r.z = __uint_as_float((u.y & 0xFFFFu) << 16);
    r.w = __uint_as_float(u.y & 0xFFFF0000u);
    return r;
}
__device__ __forceinline__ void store4(float* p, float4 v) { *(float4*)p = v; }
__device__ __forceinline__ void store4(bf16* p, float4 v) {
    uint2 u;
    u.x = (unsigned int)f2bf(v.x) | ((unsigned int)f2bf(v.y) << 16);
    u.y = (unsigned int)f2bf(v.z) | ((unsigned int)f2bf(v.w) << 16);
    *(uint2*)p = u;
}

typedef __attribute__((ext_vector_type(8))) short bf16x8;
typedef __attribute__((ext_vector_type(4))) float f32x4;

// ---------------------------------------------------------------------------
// Prep kernels (run once, ~25us total): cast x f32->bf16 (RNE, identical to
// the old staging-time conversion) and transpose-cast the weight matrices so
// the GEMM B-operand is k-contiguous bf16 (kills the Bs-transpose staging
// that caused SQ_LDS_BANK_CONFLICT=1.78e8: n-stride-16 lanes -> bank stride
// (16*20)%32 = 0, an 8-way conflict per scalar store).
// ---------------------------------------------------------------------------
__global__ __launch_bounds__(256) void cast_x_kernel(const float* __restrict__ src,
                                                     bf16* __restrict__ dst, int n8) {
    int i = blockIdx.x * 256 + threadIdx.x;
    if (i >= n8) return;
    const float* p = src + (size_t)i * 8;
    bf16* q = dst + (size_t)i * 8;
    store4(q, load4(p));
    store4(q + 4, load4(p + 4));
}

// src: f32 [R][C]  ->  dst: bf16 [C][R]   (64x64 LDS tiles)
__global__ __launch_bounds__(256) void transpose_cast_kernel(
        const float* __restrict__ src, bf16* __restrict__ dst, int R, int C) {
    __shared__ short t64[64][65];
    const int tid = threadIdx.x;
    const int r0 = blockIdx.y * 64;
    const int c0 = blockIdx.x * 64;
    const int rr = tid >> 4;           // 0..15
    const int c4 = (tid & 15) * 4;     // 0..60

    #pragma unroll
    for (int p = 0; p < 4; ++p) {
        int r = rr + p * 16;
        float4 v = load4(src + (size_t)(r0 + r) * C + c0 + c4);
        t64[r][c4 + 0] = (short)f2bf(v.x);
        t64[r][c4 + 1] = (short)f2bf(v.y);
        t64[r][c4 + 2] = (short)f2bf(v.z);
        t64[r][c4 + 3] = (short)f2bf(v.w);
    }
    __syncthreads();
    #pragma unroll
    for (int p = 0; p < 4; ++p) {
        int cc = rr + p * 16;          // output row = c0+cc
        unsigned int s0 = (unsigned short)t64[c4 + 0][cc] |
                          ((unsigned int)(unsigned short)t64[c4 + 1][cc] << 16);
        unsigned int s1 = (unsigned short)t64[c4 + 2][cc] |
                          ((unsigned int)(unsigned short)t64[c4 + 3][cc] << 16);
        uint2 u = make_uint2(s0, s1);
        *(uint2*)&dst[(size_t)(c0 + cc) * R + r0 + c4] = u;
    }
}

// ---------------------------------------------------------------------------
// MFMA bf16 GEMM, both operands pre-cast bf16, B pre-transposed [N][K]:
// staging is pure 16B vector copies (<=2-way bank aliasing = free), no
// conversions in the hot loop. 128x128 tile, BK=32, 4 waves.
// ---------------------------------------------------------------------------
template <typename TC>
__global__ __launch_bounds__(256) void gemm_bt(const bf16* __restrict__ A,
                                               const bf16* __restrict__ BT,
                                               TC* __restrict__ C,
                                               int N, int K, int lda, int ldb) {
    __shared__ short As[128 * 40];   // As[m][k], k contiguous
    __shared__ short Bs[128 * 40];   // Bs[n][k], k contiguous

    const int tid = threadIdx.x;
    const int m0 = blockIdx.y * 128;
    const int n0 = blockIdx.x * 128;

    const int row = tid >> 1;          // 0..127 (same mapping for A and B)
    const int ks  = (tid & 1) * 16;    // 0 or 16

    const int wid = tid >> 6;
    const int wx = wid & 1, wy = wid >> 1; // 2x2 wave grid
    const int lane = tid & 63;
    const int c16 = lane & 15;
    const int quad = lane >> 4;

    const bf16* Ap = A + (size_t)(m0 + row) * lda + ks;
    const bf16* Bp = BT + (size_t)(n0 + row) * ldb + ks;

    f32x4 acc[4][4];
    #pragma unroll
    for (int i = 0; i < 4; ++i)
        #pragma unroll
        for (int j = 0; j < 4; ++j) acc[i][j] = (f32x4){0.f, 0.f, 0.f, 0.f};

    uint4 ra0 = *(const uint4*)Ap;
    uint4 ra1 = *(const uint4*)(Ap + 8);
    uint4 rb0 = *(const uint4*)Bp;
    uint4 rb1 = *(const uint4*)(Bp + 8);

    for (int k0 = 0; k0 < K; k0 += 32) {
        __syncthreads();
        *(uint4*)&As[row * 40 + ks]     = ra0;
        *(uint4*)&As[row * 40 + ks + 8] = ra1;
        *(uint4*)&Bs[row * 40 + ks]     = rb0;
        *(uint4*)&Bs[row * 40 + ks + 8] = rb1;
        __syncthreads();

        if (k0 + 32 < K) {
            ra0 = *(const uint4*)(Ap + k0 + 32);
            ra1 = *(const uint4*)(Ap + k0 + 40);
            rb0 = *(const uint4*)(Bp + k0 + 32);
            rb1 = *(const uint4*)(Bp + k0 + 40);
        }

        bf16x8 af[4], bfr[4];
        #pragma unroll
        for (int mt = 0; mt < 4; ++mt)
            af[mt] = *(const bf16x8*)&As[(wy * 64 + mt * 16 + c16) * 40 + quad * 8];
        #pragma unroll
        for (int nt = 0; nt < 4; ++nt)
            bfr[nt] = *(const bf16x8*)&Bs[(wx * 64 + nt * 16 + c16) * 40 + quad * 8];

        #pragma unroll
        for (int mt = 0; mt < 4; ++mt)
            #pragma unroll
            for (int nt = 0; nt < 4; ++nt)
                acc[mt][nt] = __builtin_amdgcn_mfma_f32_16x16x32_bf16(
                    af[mt], bfr[nt], acc[mt][nt], 0, 0, 0);
    }

    #pragma unroll
    for (int mt = 0; mt < 4; ++mt) {
        #pragma unroll
        for (int r = 0; r < 4; ++r) {
            int rowc = m0 + wy * 64 + mt * 16 + quad * 4 + r;
            TC* cp = C + (size_t)rowc * N + n0 + wx * 64;
            #pragma unroll
            for (int nt = 0; nt < 4; ++nt)
                cp[nt * 16 + c16] = (TC)acc[mt][nt][r];
        }
    }
}

// ---------------------------------------------------------------------------
// Recurrence (R5 version, measured 1146-1155us): 4 waves per (b,h) chain,
// readlane broadcasts, LDS only for partial exchanges, pinned weights,
// LDS occupancy pad (relaxes RA pressure target; VGPR 44 -> 88).
// ---------------------------------------------------------------------------
__device__ __forceinline__ float lane_bcast(float v, int lane) {
    return __int_as_float(__builtin_amdgcn_readlane(__float_as_int(v), lane));
}

#define RPT16(M) M(0) M(1) M(2) M(3) M(4) M(5) M(6) M(7) \
                 M(8) M(9) M(10) M(11) M(12) M(13) M(14) M(15)

__global__ __launch_bounds__(256, 1)
__attribute__((amdgpu_waves_per_eu(1, 2)))
void recur_kernel(bf16* __restrict__ proj, const float* __restrict__ sw) {
    const int tid = threadIdx.x;
    const int e = tid & 63;
    const int w = __builtin_amdgcn_readfirstlane(tid >> 6);   // 0..3
    const int d0 = w << 4;
    const int bh = blockIdx.x;              // 0..127
    const int b = bh >> 4;
    const int h = bh & 15;

    __shared__ float2 part_rf[4][64];
    __shared__ float  part_c[4][64];
    __shared__ char lds_force[60 * 1024];
    asm volatile("" :: "v"((unsigned int)(size_t)lds_force));

    const float* Wc_p = sw + (size_t)h * 4096 + (size_t)d0 * 64 + e;
    const float* Wf_p = Wc_p + (size_t)16 * 4096;
    const float* Wr_p = Wc_p + (size_t)32 * 4096;

    #define DECLW(i) float wc##i, wf##i, wr##i;
    RPT16(DECLW)
    #undef DECLW
    #define LOADW(i) wc##i = Wc_p[(i) * 64]; \
                     wf##i = Wf_p[(i) * 64]; \
                     wr##i = Wr_p[(i) * 64];
    RPT16(LOADW)
    #undef LOADW
    #define PINW(i) asm volatile("" : "+v"(wc##i), "+v"(wf##i), "+v"(wr##i));
    RPT16(PINW)
    #undef PINW

    bf16* xi_p = proj + (size_t)b * S_ * PROJ4 + h * 64 + e;

    f32x4 rxi, rxf, rxr;
    #define PRELOAD(U) { const bf16* p = xi_p + (size_t)(U) * PROJ4; \
        rxi[U] = __bfloat162float(p[0]); \
        rxf[U] = __bfloat162float(p[1024]); \
        rxr[U] = __bfloat162float(p[2048]); }
    PRELOAD(0) PRELOAD(1) PRELOAD(2) PRELOAD(3)
    #undef PRELOAD

    float hreg = 0.0f;

    const bf16* ld = xi_p + (size_t)4 * PROJ4;
    bf16*       st = xi_p;

    #define P1T(i, A) { float hb = lane_bcast(hreg, d0 + (i)); \
        aR##A = fmaf(hb, wr##i, aR##A); \
        aF##A = fmaf(hb, wf##i, aF##A); }
    #define P2T(i, A) { float qb = lane_bcast(rh, d0 + (i)); \
        aC##A = fmaf(qb, wc##i, aC##A); }

    #define STEP(U, REFILL) { \
        float xi0 = rxi[U], xf0 = rxf[U], xr0 = rxr[U]; \
        if (REFILL) { \
            const bf16* p = ld + (size_t)(U) * PROJ4; \
            rxi[U] = __bfloat162float(p[0]); \
            rxf[U] = __bfloat162float(p[1024]); \
            rxr[U] = __bfloat162float(p[2048]); \
        } \
        float aR0 = 0.f, aR1 = 0.f, aF0 = 0.f, aF1 = 0.f; \
        P1T(0,0)  P1T(1,1)  P1T(2,0)  P1T(3,1) \
        P1T(4,0)  P1T(5,1)  P1T(6,0)  P1T(7,1) \
        P1T(8,0)  P1T(9,1)  P1T(10,0) P1T(11,1) \
        P1T(12,0) P1T(13,1) P1T(14,0) P1T(15,1) \
        part_rf[w][e] = make_float2(aR0 + aR1, aF0 + aF1); \
        BARRIER_LGKM(); \
        float2 p0 = part_rf[0][e], p1 = part_rf[1][e]; \
        float2 p2 = part_rf[2][e], p3 = part_rf[3][e]; \
        float sr = xr0 + (p0.x + p1.x) + (p2.x + p3.x); \
        float sf = xf0 + (p0.y + p1.y) + (p2.y + p3.y); \
        float r = 1.f / (1.f + __expf(-sr)); \
        float f = 1.f / (1.f + __expf(-sf)); \
        float rh = r * hreg; \
        float aC0 = 0.f, aC1 = 0.f; \
        P2T(0,0)  P2T(1,1)  P2T(2,0)  P2T(3,1) \
        P2T(4,0)  P2T(5,1)  P2T(6,0)  P2T(7,1) \
        P2T(8,0)  P2T(9,1)  P2T(10,0) P2T(11,1) \
        P2T(12,0) P2T(13,1) P2T(14,0) P2T(15,1) \
        part_c[w][e] = aC0 + aC1; \
        BARRIER_LGKM(); \
        float sc = xi0 + (part_c[0][e] + part_c[1][e]) \
                       + (part_c[2][e] + part_c[3][e]); \
        sc = fminf(fmaxf(sc, -15.f), 15.f); \
        float ex = __expf(-2.f * sc); \
        float cc = (1.f - ex) / (1.f + ex); \
        hreg = f * hreg + (1.f - f) * cc; \
        if (w == (U)) st[(size_t)(U) * PROJ4] = __float2bfloat16(hreg); \
    }

    for (int t0 = 0; t0 < S_ - 4; t0 += 4) {
        STEP(0, 1) STEP(1, 1) STEP(2, 1) STEP(3, 1)
        ld += (size_t)4 * PROJ4;
        st += (size_t)4 * PROJ4;
    }
    STEP(0, 0) STEP(1, 0) STEP(2, 0) STEP(3, 0)

    #undef STEP
    #undef P1T
    #undef P2T
}

// ---------------------------------------------------------------------------
// Gated RMSNorm in place over proj cols [0:1024).
// ---------------------------------------------------------------------------
__global__ __launch_bounds__(256) void gate_norm_kernel(bf16* __restrict__ proj,
                                                        const float* __restrict__ nw) {
    const int row = blockIdx.x;
    const int tid = threadIdx.x;
    __shared__ float red[4];

    bf16* hp = proj + (size_t)row * PROJ4;
    const bf16* gp = hp + 3 * DSTATE;

    float4 hv = load4(hp + tid * 4);
    float4 gv = load4(gp + tid * 4);

    float v0 = hv.x * (gv.x / (1.f + __expf(-gv.x)));
    float v1 = hv.y * (gv.y / (1.f + __expf(-gv.y)));
    float v2 = hv.z * (gv.z / (1.f + __expf(-gv.z)));
    float v3 = hv.w * (gv.w / (1.f + __expf(-gv.w)));

    float ss = v0 * v0 + v1 * v1 + v2 * v2 + v3 * v3;
    #pragma unroll
    for (int mask = 32; mask >= 1; mask >>= 1)
        ss += __shfl_xor(ss, mask, 64);

    const int wid = tid >> 6;
    if ((tid & 63) == 0) red[wid] = ss;
    __syncthreads();
    float tot = red[0] + red[1] + red[2] + red[3];
    float scale = rsqrtf(tot * (1.0f / (float)DSTATE) + 1e-6f);

    float4 nv = *(const float4*)(nw + tid * 4);
    float4 y;
    y.x = v0 * scale * nv.x;
    y.y = v1 * scale * nv.y;
    y.z = v2 * scale * nv.z;
    y.w = v3 * scale * nv.w;
    store4(hp + tid * 4, y);
}

// ---------------------------------------------------------------------------
extern "C" void kernel_launch(void* const* d_in, const int* in_sizes, int n_in,
                              void* d_out, int out_size, void* d_ws, size_t ws_size,
                              hipStream_t stream) {
    const float* x     = (const float*)d_in[0];   // [B,S,DIN]
    const float* w_in  = (const float*)d_in[1];   // [DIN, 4*DSTATE]
    const float* sw    = (const float*)d_in[2];   // [3H, DH, DH]
    const float* nw    = (const float*)d_in[3];   // [DSTATE]
    const float* w_out = (const float*)d_in[4];   // [DSTATE, DOUT]
    float* out = (float*)d_out;

    // Workspace layout (bytes):
    //   proj   [16384, 4096] bf16 : 134,217,728
    //   xb     [16384, 1024] bf16 :  33,554,432
    //   w_inT  [4096, 1024]  bf16 :   8,388,608
    //   w_outT [1024, 1024]  bf16 :   2,097,152    total ~170 MB
    char* ws = (char*)d_ws;
    bf16* proj   = (bf16*)ws;
    bf16* xb     = (bf16*)(ws + 134217728);
    bf16* w_inT  = (bf16*)(ws + 134217728 + 33554432);
    bf16* w_outT = (bf16*)(ws + 134217728 + 33554432 + 8388608);

    // 0) prep: cast x -> bf16; transpose-cast weights -> bf16 [N][K]
    cast_x_kernel<<<(B_ * S_ * DIN / 8 + 255) / 256, 256, 0, stream>>>(x, xb,
                                                                B_ * S_ * DIN / 8);
    transpose_cast_kernel<<<dim3(PROJ4 / 64, DIN / 64), 256, 0, stream>>>(
        w_in, w_inT, DIN, PROJ4);
    transpose_cast_kernel<<<dim3(DSTATE / 64, DSTATE / 64), 256, 0, stream>>>(
        w_out, w_outT, DSTATE, DSTATE);

    // 1) input projection: [16384,1024]bf16 @ [1024,4096] -> proj bf16
    gemm_bt<bf16><<<dim3(PROJ4 / 128, (B_ * S_) / 128), 256, 0, stream>>>(
        xb, w_inT, proj, PROJ4, DIN, DIN, DIN);

    // 2) sequential gated recurrence (unchanged, 1150us)
    recur_kernel<<<128, 256, 0, stream>>>(proj, sw);

    // 3) gate + rmsnorm in place
    gate_norm_kernel<<<B_ * S_, 256, 0, stream>>>(proj, nw);

    // 4) output projection: proj(bf16, lda=4096) @ [1024,1024] -> out f32
    gemm_bt<float><<<dim3(DSTATE / 128, (B_ * S_) / 128), 256, 0, stream>>>(
        proj, w_outT, out, DSTATE, DSTATE, PROJ4, DSTATE);
}